// Round 8
// baseline (35.410 us; speedup 1.0000x reference)
//
#include <hip/hip_runtime.h>
#include <math.h>

#define BATCH 32
#define H 512
#define W 512
#define PAD 15
#define R 4                         /* output rows per wave */
#define BANDS (H / R)               /* 128 */
#define NWAVES (BATCH * BANDS)      /* 4096 */
#define WPB 4                       /* waves per block */
#define NBLOCKS (NWAVES / WPB)      /* 1024 */
#define NXCD 8
#define INV_KK (1.0f / 961.0f)

/* fused weight + stable BCE for one element */
#define EMIT(tv, lv, hs)                                                      \
    {                                                                         \
        float pooled_ = (hs) * INV_KK;                                        \
        float wgt_ = fmaf(5.f, fabsf(pooled_ - (tv)), 1.f);                   \
        float al_ = fabsf(lv);                                                \
        float bce_ = fmaxf((lv), 0.f) - (lv) * (tv)                           \
                     + __logf(1.f + __expf(-al_));                            \
        num = fmaf(wgt_, bce_, num);                                          \
        den += wgt_;                                                          \
    }

/* one k-slot of the horizontal 31-window:
   hs = [suffix of lane l-2 after k] + base + [prefix of lane l+2 through k-1]
   aa identity: pm2_[7]-pm2_[k] == shfl_up(tot-p_[k], 2)  (bit-identical) */
#define KSLOT(pk, pkm1, tv, lv, FIRST, LAST)                                  \
    {                                                                         \
        float hs_ = base_;                                                    \
        if (!(LAST)) {                                                        \
            float sa_ = __shfl_up(tot_ - (pk), 2);                            \
            hs_ += okm2 ? sa_ : 0.f;                                          \
        }                                                                     \
        if (!(FIRST)) {                                                       \
            float se_ = __shfl_down((pkm1), 2);                               \
            hs_ += okp2 ? se_ : 0.f;                                          \
        }                                                                     \
        EMIT(tv, lv, hs_)                                                     \
    }

/* Per-row fused pass: low-pressure form (no shuffle arrays).
   Window math verified bit-identical to R2..R7 form (absmax 0). */
#define ROW_BODY(va, vb, yy)                                                  \
    {                                                                         \
        const float4* tp_ = (const float4*)(tb + (size_t)(yy) * W + x0);      \
        const float4* lp_ = (const float4*)(lb + (size_t)(yy) * W + x0);      \
        float4 t0_ = tp_[0], t1_ = tp_[1];                                    \
        float4 l0_ = lp_[0], l1_ = lp_[1];                                    \
        const float p0_ = (va).x;                                             \
        const float p1_ = p0_ + (va).y;                                       \
        const float p2_ = p1_ + (va).z;                                       \
        const float p3_ = p2_ + (va).w;                                       \
        const float p4_ = p3_ + (vb).x;                                       \
        const float p5_ = p4_ + (vb).y;                                       \
        const float p6_ = p5_ + (vb).z;                                       \
        const float tot_ = p6_ + (vb).w;                                      \
        const float bm_ = __shfl_up(tot_, 1);                                 \
        const float dp_ = __shfl_down(tot_, 1);                               \
        const float base_ = (okm1 ? bm_ : 0.f) + tot_ + (okp1 ? dp_ : 0.f);   \
        KSLOT(p0_, 0.f, t0_.x, l0_.x, 1, 0)                                   \
        KSLOT(p1_, p0_, t0_.y, l0_.y, 0, 0)                                   \
        KSLOT(p2_, p1_, t0_.z, l0_.z, 0, 0)                                   \
        KSLOT(p3_, p2_, t0_.w, l0_.w, 0, 0)                                   \
        KSLOT(p4_, p3_, t1_.x, l1_.x, 0, 0)                                   \
        KSLOT(p5_, p4_, t1_.y, l1_.y, 0, 0)                                   \
        KSLOT(p6_, p5_, t1_.z, l1_.z, 0, 0)                                   \
        KSLOT(0.f, p6_, t1_.w, l1_.w, 0, 1)                                   \
    }

#define LOAD_FAST(ra, rb, y)                                                  \
    { const float4* p_ = (const float4*)(tb + (size_t)(y) * W + x0);          \
      ra = p_[0]; rb = p_[1]; }

#define LOAD_SAFE(ra, rb, y)                                                  \
    { ra = make_float4(0.f, 0.f, 0.f, 0.f); rb = ra;                          \
      if ((unsigned)(y) < (unsigned)H) {                                      \
          const float4* p_ = (const float4*)(tb + (size_t)(y) * W + x0);      \
          ra = p_[0]; rb = p_[1]; } }

/* sum rows y0-15 .. y0+15 into (va_, vb_); 8-row chunks (16 loads in flight) */
#define CHUNKV(LOADER, C0, C1)                                                \
    _Pragma("unroll")                                                         \
    for (int c = (C0); c < (C1); ++c) {                                       \
        const int y = y0 + c - PAD;                                           \
        float4 ra, rb;                                                        \
        LOADER(ra, rb, y)                                                     \
        va_ += ra; vb_ += rb;                                                 \
    }

#define STREAM31(LOADER)                                                      \
    CHUNKV(LOADER, 0, 8)   __builtin_amdgcn_sched_barrier(0);                 \
    CHUNKV(LOADER, 8, 16)  __builtin_amdgcn_sched_barrier(0);                 \
    CHUNKV(LOADER, 16, 24) __builtin_amdgcn_sched_barrier(0);                 \
    CHUNKV(LOADER, 24, 31)

/* slide + ROW_BODY; prefetch enter/leave rows before the math that hides them */
#define PHASE_B(LOADER)                                                       \
    {                                                                         \
        float4 e0a, e0b, l0a, l0b;                                            \
        LOADER(e0a, e0b, y0 + 16) LOADER(l0a, l0b, y0 - 15)                   \
        ROW_BODY(va_, vb_, y0 + 0)                                            \
        va_ += e0a - l0a; vb_ += e0b - l0b;                                   \
        float4 e1a, e1b, l1a, l1b;                                            \
        LOADER(e1a, e1b, y0 + 17) LOADER(l1a, l1b, y0 - 14)                   \
        ROW_BODY(va_, vb_, y0 + 1)                                            \
        va_ += e1a - l1a; vb_ += e1b - l1b;                                   \
        float4 e2a, e2b, l2a, l2b;                                            \
        LOADER(e2a, e2b, y0 + 18) LOADER(l2a, l2b, y0 - 13)                   \
        ROW_BODY(va_, vb_, y0 + 2)                                            \
        va_ += e2a - l2a; vb_ += e2b - l2b;                                   \
        ROW_BODY(va_, vb_, y0 + 3)                                            \
    }

__global__ __launch_bounds__(WPB * 64)
void wbce_wave_kernel(const float* __restrict__ logits,
                      const float* __restrict__ targets,
                      float* __restrict__ partials) {
    __shared__ float rn[WPB], rd[WPB];

    const int tid  = threadIdx.x;
    const int lane = tid & 63;
    const int w    = tid >> 6;

    /* XCD-aware bijective swizzle: 128 consecutive blocks (4 images) per XCD */
    const int bid  = (int)blockIdx.x;
    const int sbid = (bid & (NXCD - 1)) * (NBLOCKS / NXCD) + (bid >> 3);

    const int wid  = sbid * WPB + w;
    const int img  = wid >> 7;            /* wid / BANDS */
    const int band = wid & (BANDS - 1);
    const int y0   = band * R;
    const int x0   = lane * 8;

    const float* tb = targets + (size_t)img * H * W;
    const float* lb = logits  + (size_t)img * H * W;

    const bool okm2 = lane >= 2, okm1 = lane >= 1;
    const bool okp1 = lane <= 62, okp2 = lane <= 61;
    float num = 0.f, den = 0.f;

    float4 va_ = {0, 0, 0, 0}, vb_ = {0, 0, 0, 0};

    if (y0 >= PAD && y0 + 19 <= H) {      /* interior band: no bounds checks */
        STREAM31(LOAD_FAST)
        PHASE_B(LOAD_FAST)
    } else {
        STREAM31(LOAD_SAFE)
        PHASE_B(LOAD_SAFE)
    }

    /* ---- wave + block reduction, one partial pair per block ---- */
    #pragma unroll
    for (int off = 32; off > 0; off >>= 1) {
        num += __shfl_down(num, off);
        den += __shfl_down(den, off);
    }
    if (lane == 0) { rn[w] = num; rd[w] = den; }
    __syncthreads();
    if (tid == 0) {
        float n = 0.f, d = 0.f;
        #pragma unroll
        for (int i = 0; i < WPB; ++i) { n += rn[i]; d += rd[i]; }
        partials[sbid * 2]     = n;
        partials[sbid * 2 + 1] = d;
    }
}

/* 1024 partial pairs -> scalar. Image i owns pairs [i*32, i*32+32). */
__global__ __launch_bounds__(1024)
void wbce_finalize_kernel(const float* __restrict__ partials,
                          float* __restrict__ out) {
    __shared__ float rsum[16];
    const int t = threadIdx.x;
    float num = partials[t * 2];
    float den = partials[t * 2 + 1];
    #pragma unroll
    for (int off = 16; off > 0; off >>= 1) {
        num += __shfl_down(num, off, 32);
        den += __shfl_down(den, off, 32);
    }
    float ratio = 0.f;
    if ((t & 31) == 0) ratio = num / den;
    ratio += __shfl_down(ratio, 32);          /* lane0 += lane32 */
    const int lane = t & 63;
    const int wv = t >> 6;
    if (lane == 0) rsum[wv] = ratio;
    __syncthreads();
    if (t == 0) {
        float s = 0.f;
        #pragma unroll
        for (int i = 0; i < 16; ++i) s += rsum[i];
        out[0] = s / (float)BATCH;
    }
}

extern "C" void kernel_launch(void* const* d_in, const int* in_sizes, int n_in,
                              void* d_out, int out_size, void* d_ws, size_t ws_size,
                              hipStream_t stream) {
    const float* logits  = (const float*)d_in[0];
    const float* targets = (const float*)d_in[1];
    float* out = (float*)d_out;
    float* partials = (float*)d_ws;   /* NBLOCKS*2 floats = 8 KB */

    wbce_wave_kernel<<<NBLOCKS, WPB * 64, 0, stream>>>(logits, targets, partials);
    wbce_finalize_kernel<<<1, 1024, 0, stream>>>(partials, out);
}